// Round 7
// baseline (257.794 us; speedup 1.0000x reference)
//
#include <hip/hip_runtime.h>
#include <hip/hip_bf16.h>
#include <stdint.h>

#define B_ 2
#define T_ 2048
#define D_ 1024
#define H_ 16
#define DEPTH 64

typedef unsigned short u16;
typedef unsigned int u32;
typedef short bf16x8 __attribute__((ext_vector_type(8)));
typedef float f32x4 __attribute__((ext_vector_type(4)));

#define MFMA16(a, b, c) __builtin_amdgcn_mfma_f32_16x16x32_bf16(a, b, c, 0, 0, 0)

// async global->LDS, 16B per lane; LDS dest = wave-uniform base + lane*16
#define GLOAD_LDS(g, l)                                                      \
    __builtin_amdgcn_global_load_lds(                                        \
        (__attribute__((address_space(1))) void*)(g),                        \
        (__attribute__((address_space(3))) void*)(l), 16, 0, 0)

__device__ __forceinline__ u16 f2bf(float f) {
    union { float f; u32 i; } x; x.f = f;
    u32 r = x.i + 0x7fffu + ((x.i >> 16) & 1u);
    return (u16)(r >> 16);
}
__device__ __forceinline__ uint2 pk4(float4 f) {
    return make_uint2((u32)f2bf(f.x) | ((u32)f2bf(f.y) << 16),
                      (u32)f2bf(f.z) | ((u32)f2bf(f.w) << 16));
}
// round-half-up pack of two floats to packed bf16x2 (2 VALU/value)
__device__ __forceinline__ u32 pkfast(float a, float b) {
    union { float f; u32 i; } x, y; x.f = a; y.f = b;
    return ((y.i + 0x8000u) & 0xffff0000u) | ((x.i + 0x8000u) >> 16);
}

// ---------------------------------------------------------------------------
// fp32 -> bf16 convert: X (q,k,v: 4M each) and W (wq,wk,wv: 1M each)
// ---------------------------------------------------------------------------
__global__ __launch_bounds__(256) void conv_kernel(
    const float* __restrict__ s0, const float* __restrict__ s1, const float* __restrict__ s2,
    const float* __restrict__ s3, const float* __restrict__ s4, const float* __restrict__ s5,
    u16* __restrict__ xbf, u16* __restrict__ wbf)
{
    const int z = blockIdx.y;
    const float* src = (z == 0) ? s0 : (z == 1) ? s1 : (z == 2) ? s2
                     : (z == 3) ? s3 : (z == 4) ? s4 : s5;
    u16* dst = (z < 3) ? (xbf + (size_t)z * 4194304) : (wbf + (size_t)(z - 3) * 1048576);
    const size_t nel = (z < 3) ? 4194304u : 1048576u;
    for (size_t i = ((size_t)blockIdx.x * 256 + threadIdx.x) * 8; i < nel;
         i += (size_t)gridDim.x * 2048) {
        float4 a = *(const float4*)(src + i);
        float4 b = *(const float4*)(src + i + 4);
        uint2 lo = pk4(a), hi = pk4(b);
        *(uint4*)(dst + i) = make_uint4(lo.x, lo.y, hi.x, hi.y);
    }
}

// ---------------------------------------------------------------------------
// Projection: bf16 X[4096,1024] @ W^T[1024,1024] + bias. 128x128 tile, BK=64,
// global_load_lds width-16, XOR chunk swizzle, DOUBLE-BUFFERED single-barrier
// K-loop (prefetch k0+64 after barrier; vmcnt drain at next barrier has a full
// tile of compute to hide behind). Q/K head-split [h*B+b][t][64]; V transposed
// [h*B+b][64][T].
// ---------------------------------------------------------------------------
__global__ __launch_bounds__(256, 2) void proj_mfma(
    const u16* __restrict__ xbf, const u16* __restrict__ wbf,
    const float* __restrict__ bq, const float* __restrict__ bk, const float* __restrict__ bv,
    u16* __restrict__ qh, u16* __restrict__ kh, u16* __restrict__ vt)
{
    __shared__ __attribute__((aligned(16))) u16 As[2][128 * 64];
    __shared__ __attribute__((aligned(16))) u16 Bs[2][128 * 64];

    const int z = blockIdx.z;
    const u16* A = xbf + (size_t)z * 4194304;
    const u16* W = wbf + (size_t)z * 1048576;
    const float* bias = (z == 0) ? bq : (z == 1) ? bk : bv;

    const int tid = threadIdx.x, w = tid >> 6, lane = tid & 63;
    const int quad = lane >> 4, l16 = lane & 15;
    const int m0 = blockIdx.y * 128, n0 = blockIdx.x * 128;
    const int wm = (w & 1) * 64, wn = (w >> 1) * 64;
    const int srow = lane >> 3;                 // 0..7
    const int schunk = (lane & 7) ^ srow;       // xor-swizzled source chunk

    f32x4 acc[4][4];
    #pragma unroll
    for (int mi = 0; mi < 4; ++mi)
        #pragma unroll
        for (int ni = 0; ni < 4; ++ni) acc[mi][ni] = (f32x4){0.f, 0.f, 0.f, 0.f};

    const size_t ar = (size_t)(m0 + 32 * w + srow);
    const size_t br = (size_t)(n0 + 32 * w + srow);

#define PROJ_STAGE(K0, BUF)                                                   \
    {                                                                         \
        _Pragma("unroll")                                                     \
        for (int i_ = 0; i_ < 4; ++i_) {                                      \
            GLOAD_LDS(A + (ar + 8 * i_) * D_ + (K0) + schunk * 8,             \
                      &As[(BUF)][(32 * w + 8 * i_) * 64]);                    \
            GLOAD_LDS(W + (br + 8 * i_) * D_ + (K0) + schunk * 8,             \
                      &Bs[(BUF)][(32 * w + 8 * i_) * 64]);                    \
        }                                                                     \
    }

    PROJ_STAGE(0, 0);   // prologue

    for (int k0 = 0; k0 < D_; k0 += 64) {
        const int cur = (k0 >> 6) & 1;
        __syncthreads();                      // drains vmcnt -> buf[cur] ready
        if (k0 + 64 < D_) PROJ_STAGE(k0 + 64, cur ^ 1);

        #pragma unroll
        for (int kg = 0; kg < 2; ++kg) {
            const int ch = ((4 * kg + quad) ^ (l16 & 7)) * 8;
            bf16x8 af[4], bf[4];
            #pragma unroll
            for (int mi = 0; mi < 4; ++mi)
                af[mi] = *(const bf16x8*)&As[cur][(wm + 16 * mi + l16) * 64 + ch];
            #pragma unroll
            for (int ni = 0; ni < 4; ++ni)
                bf[ni] = *(const bf16x8*)&Bs[cur][(wn + 16 * ni + l16) * 64 + ch];
            #pragma unroll
            for (int mi = 0; mi < 4; ++mi)
                #pragma unroll
                for (int ni = 0; ni < 4; ++ni)
                    acc[mi][ni] = MFMA16(af[mi], bf[ni], acc[mi][ni]);
        }
    }
#undef PROJ_STAGE

    float bl[4];
    #pragma unroll
    for (int ni = 0; ni < 4; ++ni) bl[ni] = bias[n0 + wn + ni * 16 + l16];

    #pragma unroll
    for (int mi = 0; mi < 4; ++mi) {
        const int mb = m0 + wm + mi * 16 + quad * 4;
        #pragma unroll
        for (int ni = 0; ni < 4; ++ni) {
            const int nn = n0 + wn + ni * 16 + l16;
            const int head = nn >> 6, d = nn & 63;
            if (z < 2) {
                u16* outp = (z == 0) ? qh : kh;
                #pragma unroll
                for (int r = 0; r < 4; ++r) {
                    const int m = mb + r;
                    const int b = m >> 11, t = m & (T_ - 1);
                    outp[((size_t)(head * B_ + b) * T_ + t) * DEPTH + d] =
                        f2bf(acc[mi][ni][r] + bl[ni]);
                }
            } else {
                const int b = mb >> 11, t = mb & (T_ - 1);
                float4 f = make_float4(acc[mi][ni][0] + bl[ni], acc[mi][ni][1] + bl[ni],
                                       acc[mi][ni][2] + bl[ni], acc[mi][ni][3] + bl[ni]);
                *(uint2*)(vt + ((size_t)(head * B_ + b) * DEPTH + d) * T_ + t) = pk4(f);
            }
        }
    }
}

// ---------------------------------------------------------------------------
// Flash attention, S^T formulation, fixed-max softmax, Tq=128/block (4 waves,
// 2 strips of 16 queries each). K/V DOUBLE-BUFFERED with single-barrier
// pipelined K-loop: prefetch tile t0+64 right after the barrier, compute tile
// t0 from the other buffer; the compiler's vmcnt(0)-before-barrier then waits
// on a prefetch that is a full tile old. XOR chunk swizzle, conflict-free
// b128 frag reads. V pre-transposed [n][64][T] (depth-row stride = T_).
// Mask quirk: row n uses mask[n / H].
// ---------------------------------------------------------------------------
__global__ __launch_bounds__(256, 2) void attn_kernel(
    const u16* __restrict__ qh, const u16* __restrict__ kh, const u16* __restrict__ vt,
    const int* __restrict__ maskp, const int* __restrict__ causp,
    float* __restrict__ outp)
{
    __shared__ __attribute__((aligned(16))) u16 Ks[2][64 * 64];    // [key][depth] swizzled
    __shared__ __attribute__((aligned(16))) u16 Vs[2][64 * 64];    // [depth][key] swizzled
    __shared__ __attribute__((aligned(16))) u16 Ps[4][2][16][72];  // [wave][strip][q][key]
    __shared__ __attribute__((aligned(16))) float padf[T_];        // mask*PAD (log2 units)

    const int n  = blockIdx.y;          // head*B + b
    const int qt = blockIdx.x;          // 128-query tile
    const int head = n >> 1, bi = n & 1;
    const int mrow = n >> 4;            // n / H  (reference repeat quirk)
    const int caus = causp[0];

    const int tid  = threadIdx.x;
    const int w    = tid >> 6, lane = tid & 63;
    const int quad = lane >> 4, l16 = lane & 15;
    const size_t base = (size_t)n * T_ * DEPTH;
    const size_t vbase = (size_t)n * DEPTH * T_;

    const float C1  = 0.18033688011112042f;   // (1/8) * log2(e)
    const float PL2 = -6.2e9f;                // exp2 -> 0

    // precompute pad row (once per block)
    {
        const int i0 = tid * 8;
        int4 ma = *(const int4*)(maskp + (size_t)mrow * T_ + i0);
        int4 mb = *(const int4*)(maskp + (size_t)mrow * T_ + i0 + 4);
        padf[i0 + 0] = (float)ma.x * PL2; padf[i0 + 1] = (float)ma.y * PL2;
        padf[i0 + 2] = (float)ma.z * PL2; padf[i0 + 3] = (float)ma.w * PL2;
        padf[i0 + 4] = (float)mb.x * PL2; padf[i0 + 5] = (float)mb.y * PL2;
        padf[i0 + 6] = (float)mb.z * PL2; padf[i0 + 7] = (float)mb.w * PL2;
    }

    // Q fragments: 2 strips x 2 k-halves, loop-invariant registers
    bf16x8 aq[2][2];
    #pragma unroll
    for (int s = 0; s < 2; ++s) {
        const int qg = qt * 128 + w * 32 + s * 16 + l16;
        aq[s][0] = *(const bf16x8*)(qh + base + (size_t)qg * DEPTH + quad * 8);
        aq[s][1] = *(const bf16x8*)(qh + base + (size_t)qg * DEPTH + 32 + quad * 8);
    }

    f32x4 O[2][4];
    #pragma unroll
    for (int s = 0; s < 2; ++s)
        #pragma unroll
        for (int t = 0; t < 4; ++t) O[s][t] = (f32x4){0.f, 0.f, 0.f, 0.f};
    float lp[2] = {0.f, 0.f};

    // staging addresses: wave w stages tile rows w*16..w*16+15
    const int g_row = w * 16 + (lane >> 3);           // tile row this lane feeds
    const int g_ch  = (lane & 7) ^ ((lane >> 3) & 7); // swizzled source chunk
    const u16* ksrc = kh + base + (size_t)g_row * DEPTH + g_ch * 8;
    const u16* vsrc = vt + vbase + (size_t)g_row * T_ + g_ch * 8;

#define ATTN_STAGE(T0, BUF)                                                   \
    {                                                                         \
        GLOAD_LDS(ksrc + (size_t)(T0) * DEPTH,       &Ks[(BUF)][(w * 16) * 64]);     \
        GLOAD_LDS(ksrc + (size_t)((T0) + 8) * DEPTH, &Ks[(BUF)][(w * 16 + 8) * 64]); \
        GLOAD_LDS(vsrc + (T0),                       &Vs[(BUF)][(w * 16) * 64]);     \
        GLOAD_LDS(vsrc + (size_t)8 * T_ + (T0),      &Vs[(BUF)][(w * 16 + 8) * 64]); \
    }

    ATTN_STAGE(0, 0);   // prologue

    for (int t0 = 0; t0 < T_; t0 += 64) {
        const int cur = (t0 >> 6) & 1;
        __syncthreads();                      // drains vmcnt -> buf[cur] ready
        if (t0 + 64 < T_) ATTN_STAGE(t0 + 64, cur ^ 1);

        // S^T per 16-key subtile; exp; P -> LDS
        const int swz = (l16 & 7);
        #pragma unroll
        for (int t = 0; t < 4; ++t) {
            const int krow = t * 16 + l16;
            bf16x8 kb0 = *(const bf16x8*)&Ks[cur][krow * 64 + ((quad ^ swz) * 8)];
            bf16x8 kb1 = *(const bf16x8*)&Ks[cur][krow * 64 + (((4 + quad) ^ swz) * 8)];
            f32x4 pv4 = *(const f32x4*)&padf[t0 + t * 16 + quad * 4];
            #pragma unroll
            for (int s = 0; s < 2; ++s) {
                f32x4 st = (f32x4){0.f, 0.f, 0.f, 0.f};
                st = MFMA16(kb0, aq[s][0], st);
                st = MFMA16(kb1, aq[s][1], st);
                float v0 = fmaf(st[0], C1, pv4[0]);
                float v1 = fmaf(st[1], C1, pv4[1]);
                float v2 = fmaf(st[2], C1, pv4[2]);
                float v3 = fmaf(st[3], C1, pv4[3]);
                if (caus) {
                    const int kg = t0 + t * 16 + quad * 4;
                    const int qg = qt * 128 + w * 32 + s * 16 + l16;
                    if (kg + 0 > qg) v0 = PL2;
                    if (kg + 1 > qg) v1 = PL2;
                    if (kg + 2 > qg) v2 = PL2;
                    if (kg + 3 > qg) v3 = PL2;
                }
                const float e0 = exp2f(v0), e1 = exp2f(v1);
                const float e2 = exp2f(v2), e3 = exp2f(v3);
                lp[s] += (e0 + e1) + (e2 + e3);
                *(uint2*)&Ps[w][s][l16][t * 16 + quad * 4] =
                    make_uint2(pkfast(e0, e1), pkfast(e2, e3));
            }
        }

        // PV: O[s][query][d] += P * V  (same-wave Ps reuse, no barrier)
        bf16x8 ap[2][2];
        #pragma unroll
        for (int s = 0; s < 2; ++s) {
            ap[s][0] = *(const bf16x8*)&Ps[w][s][l16][quad * 8];
            ap[s][1] = *(const bf16x8*)&Ps[w][s][l16][32 + quad * 8];
        }
        #pragma unroll
        for (int t = 0; t < 4; ++t) {
            const int drow = t * 16 + l16;
            bf16x8 vb0 = *(const bf16x8*)&Vs[cur][drow * 64 + ((quad ^ swz) * 8)];
            bf16x8 vb1 = *(const bf16x8*)&Vs[cur][drow * 64 + (((4 + quad) ^ swz) * 8)];
            #pragma unroll
            for (int s = 0; s < 2; ++s) {
                O[s][t] = MFMA16(ap[s][0], vb0, O[s][t]);
                O[s][t] = MFMA16(ap[s][1], vb1, O[s][t]);
            }
        }
    }
#undef ATTN_STAGE

    // fold l across quads (per-lane partials cover 4 keys each tile)
    #pragma unroll
    for (int s = 0; s < 2; ++s) {
        lp[s] += __shfl_xor(lp[s], 16, 64);
        lp[s] += __shfl_xor(lp[s], 32, 64);
    }

    #pragma unroll
    for (int s = 0; s < 2; ++s) {
        #pragma unroll
        for (int r = 0; r < 4; ++r) {
            const float lr  = __shfl(lp[s], quad * 4 + r, 64);
            const float inv = 1.0f / fmaxf(lr, 1e-30f);
            const size_t rb = ((size_t)bi * T_ + qt * 128 + w * 32 + s * 16 + quad * 4 + r) * D_
                            + head * DEPTH + l16;
            outp[rb + 0]  = O[s][0][r] * inv;
            outp[rb + 16] = O[s][1][r] * inv;
            outp[rb + 32] = O[s][2][r] * inv;
            outp[rb + 48] = O[s][3][r] * inv;
        }
    }
}

// ---------------------------------------------------------------------------
// LayerNorm: x = ctx(out) + q; normalize over D=1024; in-place on d_out (fp32).
// ---------------------------------------------------------------------------
__global__ __launch_bounds__(256) void ln_kernel(
    const float* __restrict__ qin,
    const float* __restrict__ gamma, const float* __restrict__ beta,
    float* __restrict__ out)
{
    const int row = blockIdx.x;
    const int tid = threadIdx.x;
    const size_t basei = (size_t)row * D_ + (tid << 2);
    float4 c  = *(const float4*)(out + basei);
    float4 qv = *(const float4*)(qin + basei);
    float x[4] = {c.x + qv.x, c.y + qv.y, c.z + qv.z, c.w + qv.w};
    float s  = x[0] + x[1] + x[2] + x[3];
    float s2 = x[0]*x[0] + x[1]*x[1] + x[2]*x[2] + x[3]*x[3];
    #pragma unroll
    for (int off = 1; off < 64; off <<= 1) {
        s  += __shfl_xor(s, off, 64);
        s2 += __shfl_xor(s2, off, 64);
    }
    __shared__ float rs[4], rs2[4];
    const int wid = tid >> 6;
    if ((tid & 63) == 0) { rs[wid] = s; rs2[wid] = s2; }
    __syncthreads();
    s  = rs[0] + rs[1] + rs[2] + rs[3];
    s2 = rs2[0] + rs2[1] + rs2[2] + rs2[3];
    const float mean = s * (1.0f / (float)D_);
    const float var  = s2 * (1.0f / (float)D_) - mean * mean;
    const float rstd = rsqrtf(var + 1e-5f);
    float4 g = *(const float4*)(gamma + (tid << 2));
    float4 b = *(const float4*)(beta + (tid << 2));
    float4 r;
    r.x = (x[0] - mean) * rstd * g.x + b.x;
    r.y = (x[1] - mean) * rstd * g.y + b.y;
    r.z = (x[2] - mean) * rstd * g.z + b.z;
    r.w = (x[3] - mean) * rstd * g.w + b.w;
    *(float4*)(out + basei) = r;
}

extern "C" void kernel_launch(void* const* d_in, const int* in_sizes, int n_in,
                              void* d_out, int out_size, void* d_ws, size_t ws_size,
                              hipStream_t stream)
{
    (void)in_sizes; (void)n_in; (void)out_size; (void)ws_size;
    const float* q    = (const float*)d_in[0];
    const float* k    = (const float*)d_in[1];
    const float* v    = (const float*)d_in[2];
    const int* mask = (const int*)d_in[3];
    const int* caus = (const int*)d_in[4];
    /* d_in[5] = edge_fea (unused) */
    const float* wq = (const float*)d_in[6];
    const float* bq = (const float*)d_in[7];
    const float* wk = (const float*)d_in[8];
    const float* bk = (const float*)d_in[9];
    const float* wv = (const float*)d_in[10];
    const float* bv = (const float*)d_in[11];
    const float* gamma = (const float*)d_in[12];
    const float* beta  = (const float*)d_in[13];
    float* out = (float*)d_out;

    const size_t elems = (size_t)B_ * T_ * D_;   // 4,194,304
    u16* qh  = (u16*)d_ws;
    u16* kh  = qh + elems;
    u16* vt  = kh + elems;                       // transposed V [n][64][T]
    u16* xbf = vt + elems;                       // bf16 X, 3 tensors
    u16* wbf = xbf + 3 * elems;                  // bf16 W, 3 tensors

    conv_kernel<<<dim3(512, 6), 256, 0, stream>>>(q, k, v, wq, wk, wv, xbf, wbf);
    proj_mfma<<<dim3(8, 32, 3), 256, 0, stream>>>(xbf, wbf, bq, bk, bv, qh, kh, vt);

    dim3 agrid(T_ / 128, H_ * B_);               // 16 x 32 = 512 blocks
    attn_kernel<<<agrid, 256, 0, stream>>>(qh, kh, vt, mask, caus, out);

    ln_kernel<<<B_ * T_, 256, 0, stream>>>(q, gamma, beta, out);
}

// Round 8
// 234.083 us; speedup vs baseline: 1.1013x; 1.1013x over previous
//
#include <hip/hip_runtime.h>
#include <hip/hip_bf16.h>
#include <stdint.h>

#define B_ 2
#define T_ 2048
#define D_ 1024
#define H_ 16
#define DEPTH 64

typedef unsigned short u16;
typedef unsigned int u32;
typedef short bf16x8 __attribute__((ext_vector_type(8)));
typedef float f32x4 __attribute__((ext_vector_type(4)));

#define MFMA16(a, b, c) __builtin_amdgcn_mfma_f32_16x16x32_bf16(a, b, c, 0, 0, 0)

// async global->LDS, 16B per lane; LDS dest = wave-uniform base + lane*16
#define GLOAD_LDS(g, l)                                                      \
    __builtin_amdgcn_global_load_lds(                                        \
        (__attribute__((address_space(1))) void*)(g),                        \
        (__attribute__((address_space(3))) void*)(l), 16, 0, 0)

__device__ __forceinline__ float bf2f(u32 u) {
    union { u32 i; float f; } x; x.i = u << 16; return x.f;
}
__device__ __forceinline__ u16 f2bf(float f) {
    union { float f; u32 i; } x; x.f = f;
    u32 r = x.i + 0x7fffu + ((x.i >> 16) & 1u);
    return (u16)(r >> 16);
}
__device__ __forceinline__ uint2 pk4(float4 f) {
    return make_uint2((u32)f2bf(f.x) | ((u32)f2bf(f.y) << 16),
                      (u32)f2bf(f.z) | ((u32)f2bf(f.w) << 16));
}
// round-half-up pack of two floats to packed bf16x2 (2 VALU/value)
__device__ __forceinline__ u32 pkfast(float a, float b) {
    union { float f; u32 i; } x, y; x.f = a; y.f = b;
    return ((y.i + 0x8000u) & 0xffff0000u) | ((x.i + 0x8000u) >> 16);
}

// ---------------------------------------------------------------------------
// fp32 -> bf16 convert: X (q,k,v: 4M each) and W (wq,wk,wv: 1M each)
// ---------------------------------------------------------------------------
__global__ __launch_bounds__(256) void conv_kernel(
    const float* __restrict__ s0, const float* __restrict__ s1, const float* __restrict__ s2,
    const float* __restrict__ s3, const float* __restrict__ s4, const float* __restrict__ s5,
    u16* __restrict__ xbf, u16* __restrict__ wbf)
{
    const int z = blockIdx.y;
    const float* src = (z == 0) ? s0 : (z == 1) ? s1 : (z == 2) ? s2
                     : (z == 3) ? s3 : (z == 4) ? s4 : s5;
    u16* dst = (z < 3) ? (xbf + (size_t)z * 4194304) : (wbf + (size_t)(z - 3) * 1048576);
    const size_t nel = (z < 3) ? 4194304u : 1048576u;
    for (size_t i = ((size_t)blockIdx.x * 256 + threadIdx.x) * 8; i < nel;
         i += (size_t)gridDim.x * 2048) {
        float4 a = *(const float4*)(src + i);
        float4 b = *(const float4*)(src + i + 4);
        uint2 lo = pk4(a), hi = pk4(b);
        *(uint4*)(dst + i) = make_uint4(lo.x, lo.y, hi.x, hi.y);
    }
}

// ---------------------------------------------------------------------------
// Projection (round-6 version: single-buffer, 3 blocks/CU): bf16 X @ W^T +
// bias. 128x128 tile, BK=64, global_load_lds width-16, XOR chunk swizzle.
// Q/K head-split [h*B+b][t][64]; V transposed [h*B+b][64][T].
// ---------------------------------------------------------------------------
__global__ __launch_bounds__(256, 3) void proj_mfma(
    const u16* __restrict__ xbf, const u16* __restrict__ wbf,
    const float* __restrict__ bq, const float* __restrict__ bk, const float* __restrict__ bv,
    u16* __restrict__ qh, u16* __restrict__ kh, u16* __restrict__ vt)
{
    __shared__ __attribute__((aligned(16))) u16 As[128 * 64];
    __shared__ __attribute__((aligned(16))) u16 Bs[128 * 64];

    const int z = blockIdx.z;
    const u16* A = xbf + (size_t)z * 4194304;
    const u16* W = wbf + (size_t)z * 1048576;
    const float* bias = (z == 0) ? bq : (z == 1) ? bk : bv;

    const int tid = threadIdx.x, w = tid >> 6, lane = tid & 63;
    const int quad = lane >> 4, l16 = lane & 15;
    const int m0 = blockIdx.y * 128, n0 = blockIdx.x * 128;
    const int wm = (w & 1) * 64, wn = (w >> 1) * 64;
    const int srow = lane >> 3;                 // 0..7
    const int schunk = (lane & 7) ^ srow;       // xor-swizzled source chunk

    f32x4 acc[4][4];
    #pragma unroll
    for (int mi = 0; mi < 4; ++mi)
        #pragma unroll
        for (int ni = 0; ni < 4; ++ni) acc[mi][ni] = (f32x4){0.f, 0.f, 0.f, 0.f};

    const size_t ar = (size_t)(m0 + 32 * w + srow);
    const size_t br = (size_t)(n0 + 32 * w + srow);

    for (int k0 = 0; k0 < D_; k0 += 64) {
        __syncthreads();
        #pragma unroll
        for (int i = 0; i < 4; ++i) {
            GLOAD_LDS(A + (ar + 8 * i) * D_ + k0 + schunk * 8, &As[(32 * w + 8 * i) * 64]);
            GLOAD_LDS(W + (br + 8 * i) * D_ + k0 + schunk * 8, &Bs[(32 * w + 8 * i) * 64]);
        }
        __syncthreads();

        #pragma unroll
        for (int kg = 0; kg < 2; ++kg) {
            const int ch = ((4 * kg + quad) ^ (l16 & 7)) * 8;
            bf16x8 af[4], bf[4];
            #pragma unroll
            for (int mi = 0; mi < 4; ++mi)
                af[mi] = *(const bf16x8*)&As[(wm + 16 * mi + l16) * 64 + ch];
            #pragma unroll
            for (int ni = 0; ni < 4; ++ni)
                bf[ni] = *(const bf16x8*)&Bs[(wn + 16 * ni + l16) * 64 + ch];
            #pragma unroll
            for (int mi = 0; mi < 4; ++mi)
                #pragma unroll
                for (int ni = 0; ni < 4; ++ni)
                    acc[mi][ni] = MFMA16(af[mi], bf[ni], acc[mi][ni]);
        }
    }

    float bl[4];
    #pragma unroll
    for (int ni = 0; ni < 4; ++ni) bl[ni] = bias[n0 + wn + ni * 16 + l16];

    #pragma unroll
    for (int mi = 0; mi < 4; ++mi) {
        const int mb = m0 + wm + mi * 16 + quad * 4;
        #pragma unroll
        for (int ni = 0; ni < 4; ++ni) {
            const int nn = n0 + wn + ni * 16 + l16;
            const int head = nn >> 6, d = nn & 63;
            if (z < 2) {
                u16* outp = (z == 0) ? qh : kh;
                #pragma unroll
                for (int r = 0; r < 4; ++r) {
                    const int m = mb + r;
                    const int b = m >> 11, t = m & (T_ - 1);
                    outp[((size_t)(head * B_ + b) * T_ + t) * DEPTH + d] =
                        f2bf(acc[mi][ni][r] + bl[ni]);
                }
            } else {
                const int b = mb >> 11, t = mb & (T_ - 1);
                float4 f = make_float4(acc[mi][ni][0] + bl[ni], acc[mi][ni][1] + bl[ni],
                                       acc[mi][ni][2] + bl[ni], acc[mi][ni][3] + bl[ni]);
                *(uint2*)(vt + ((size_t)(head * B_ + b) * DEPTH + d) * T_ + t) = pk4(f);
            }
        }
    }
}

// ---------------------------------------------------------------------------
// Flash attention, S^T form, fixed-max softmax, SPLIT-K over 2 key halves.
// Partials are exactly additive (no running max): each block computes
// O_part (bf16 -> po[kk]) and l_part (fp32 -> pl[kk]) over 1024 keys.
// Tq=128/block, 4 waves x 2 strips. Single-buffered K/V via global_load_lds,
// XOR chunk swizzle. ~30 KB LDS -> 4 blocks/CU (the round-7 latency fix).
// V pre-transposed [n][64][T]. Mask quirk: row n uses mask[n / H].
// ---------------------------------------------------------------------------
__global__ __launch_bounds__(256, 4) void attn_kernel(
    const u16* __restrict__ qh, const u16* __restrict__ kh, const u16* __restrict__ vt,
    const int* __restrict__ maskp, const int* __restrict__ causp,
    u16* __restrict__ po, float* __restrict__ pl)
{
    __shared__ __attribute__((aligned(16))) u16 Ks[64 * 64];       // [key][depth] swizzled
    __shared__ __attribute__((aligned(16))) u16 Vs[64 * 64];       // [depth][key] swizzled
    __shared__ __attribute__((aligned(16))) u16 Ps[4][2][16][72];  // [wave][strip][q][key]
    __shared__ __attribute__((aligned(16))) float padf[1024];      // mask*PAD, this half

    const int n  = blockIdx.y;          // head*B + b
    const int qt = blockIdx.x;          // 128-query tile
    const int kk = blockIdx.z;          // key half
    const int kbase = kk * 1024;
    const int head = n >> 1, bi = n & 1;
    const int mrow = n >> 4;            // n / H  (reference repeat quirk)
    const int caus = causp[0];

    const int tid  = threadIdx.x;
    const int w    = tid >> 6, lane = tid & 63;
    const int quad = lane >> 4, l16 = lane & 15;
    const size_t base = (size_t)n * T_ * DEPTH;
    const size_t vbase = (size_t)n * DEPTH * T_;
    const size_t elems = (size_t)B_ * T_ * D_;

    const float C1  = 0.18033688011112042f;   // (1/8) * log2(e)
    const float PL2 = -6.2e9f;                // exp2 -> 0

    // precompute pad row for this key half (once per block)
    {
        const int i0 = tid * 4;
        int4 m = *(const int4*)(maskp + (size_t)mrow * T_ + kbase + i0);
        padf[i0 + 0] = (float)m.x * PL2; padf[i0 + 1] = (float)m.y * PL2;
        padf[i0 + 2] = (float)m.z * PL2; padf[i0 + 3] = (float)m.w * PL2;
    }

    // Q fragments: 2 strips x 2 k-halves, loop-invariant registers
    bf16x8 aq[2][2];
    #pragma unroll
    for (int s = 0; s < 2; ++s) {
        const int qg = qt * 128 + w * 32 + s * 16 + l16;
        aq[s][0] = *(const bf16x8*)(qh + base + (size_t)qg * DEPTH + quad * 8);
        aq[s][1] = *(const bf16x8*)(qh + base + (size_t)qg * DEPTH + 32 + quad * 8);
    }

    f32x4 O[2][4];
    #pragma unroll
    for (int s = 0; s < 2; ++s)
        #pragma unroll
        for (int t = 0; t < 4; ++t) O[s][t] = (f32x4){0.f, 0.f, 0.f, 0.f};
    float lp[2] = {0.f, 0.f};

    // staging addresses: wave w stages tile rows w*16..w*16+15
    const int g_row = w * 16 + (lane >> 3);           // tile row this lane feeds
    const int g_ch  = (lane & 7) ^ ((lane >> 3) & 7); // swizzled source chunk
    const u16* ksrc = kh + base + (size_t)g_row * DEPTH + g_ch * 8;
    const u16* vsrc = vt + vbase + (size_t)g_row * T_ + g_ch * 8;

    for (int t0 = kbase; t0 < kbase + 1024; t0 += 64) {
        __syncthreads();   // prev compute done (also covers padf on 1st iter)
        GLOAD_LDS(ksrc + (size_t)t0 * DEPTH,       &Ks[(w * 16) * 64]);
        GLOAD_LDS(ksrc + (size_t)(t0 + 8) * DEPTH, &Ks[(w * 16 + 8) * 64]);
        GLOAD_LDS(vsrc + t0,                       &Vs[(w * 16) * 64]);
        GLOAD_LDS(vsrc + (size_t)8 * T_ + t0,      &Vs[(w * 16 + 8) * 64]);
        __syncthreads();

        // S^T per 16-key subtile; exp; P -> LDS
        const int swz = (l16 & 7);
        const int lt0 = t0 - kbase;
        #pragma unroll
        for (int t = 0; t < 4; ++t) {
            const int krow = t * 16 + l16;
            bf16x8 kb0 = *(const bf16x8*)&Ks[krow * 64 + ((quad ^ swz) * 8)];
            bf16x8 kb1 = *(const bf16x8*)&Ks[krow * 64 + (((4 + quad) ^ swz) * 8)];
            f32x4 pv4 = *(const f32x4*)&padf[lt0 + t * 16 + quad * 4];
            #pragma unroll
            for (int s = 0; s < 2; ++s) {
                f32x4 st = (f32x4){0.f, 0.f, 0.f, 0.f};
                st = MFMA16(kb0, aq[s][0], st);
                st = MFMA16(kb1, aq[s][1], st);
                float v0 = fmaf(st[0], C1, pv4[0]);
                float v1 = fmaf(st[1], C1, pv4[1]);
                float v2 = fmaf(st[2], C1, pv4[2]);
                float v3 = fmaf(st[3], C1, pv4[3]);
                if (caus) {
                    const int kg = t0 + t * 16 + quad * 4;
                    const int qg = qt * 128 + w * 32 + s * 16 + l16;
                    if (kg + 0 > qg) v0 = PL2;
                    if (kg + 1 > qg) v1 = PL2;
                    if (kg + 2 > qg) v2 = PL2;
                    if (kg + 3 > qg) v3 = PL2;
                }
                const float e0 = exp2f(v0), e1 = exp2f(v1);
                const float e2 = exp2f(v2), e3 = exp2f(v3);
                lp[s] += (e0 + e1) + (e2 + e3);
                *(uint2*)&Ps[w][s][l16][t * 16 + quad * 4] =
                    make_uint2(pkfast(e0, e1), pkfast(e2, e3));
            }
        }

        // PV: O[s][query][d] += P * V  (same-wave Ps reuse, no barrier)
        bf16x8 ap[2][2];
        #pragma unroll
        for (int s = 0; s < 2; ++s) {
            ap[s][0] = *(const bf16x8*)&Ps[w][s][l16][quad * 8];
            ap[s][1] = *(const bf16x8*)&Ps[w][s][l16][32 + quad * 8];
        }
        #pragma unroll
        for (int t = 0; t < 4; ++t) {
            const int drow = t * 16 + l16;
            bf16x8 vb0 = *(const bf16x8*)&Vs[drow * 64 + ((quad ^ swz) * 8)];
            bf16x8 vb1 = *(const bf16x8*)&Vs[drow * 64 + (((4 + quad) ^ swz) * 8)];
            #pragma unroll
            for (int s = 0; s < 2; ++s) {
                O[s][t] = MFMA16(ap[s][0], vb0, O[s][t]);
                O[s][t] = MFMA16(ap[s][1], vb1, O[s][t]);
            }
        }
    }

    // fold l across quads; write partial l (lanes of quad 0 cover 16 queries)
    u16* pop = po + (size_t)kk * elems;
    float* plp = pl + (size_t)kk * 32 * T_;
    #pragma unroll
    for (int s = 0; s < 2; ++s) {
        lp[s] += __shfl_xor(lp[s], 16, 64);
        lp[s] += __shfl_xor(lp[s], 32, 64);
        if (quad == 0)
            plp[(size_t)n * T_ + qt * 128 + w * 32 + s * 16 + l16] = lp[s];
    }

    // write partial O (bf16, un-normalized)
    #pragma unroll
    for (int s = 0; s < 2; ++s) {
        #pragma unroll
        for (int r = 0; r < 4; ++r) {
            const int qg = qt * 128 + w * 32 + s * 16 + quad * 4 + r;
            const size_t rb = ((size_t)bi * T_ + qg) * D_ + head * DEPTH + l16;
            pop[rb + 0]  = f2bf(O[s][0][r]);
            pop[rb + 16] = f2bf(O[s][1][r]);
            pop[rb + 32] = f2bf(O[s][2][r]);
            pop[rb + 48] = f2bf(O[s][3][r]);
        }
    }
}

// ---------------------------------------------------------------------------
// Fused combine + residual + LayerNorm: x = (po0+po1)/(l0+l1) + q; LN over D.
// One block per row (bi*T + t). Thread tid covers cols tid*4..tid*4+3 (all in
// head tid>>4, so one l-pair load per thread).
// ---------------------------------------------------------------------------
__global__ __launch_bounds__(256) void fuse_ln(
    const u16* __restrict__ po, const float* __restrict__ pl,
    const float* __restrict__ qin,
    const float* __restrict__ gamma, const float* __restrict__ beta,
    float* __restrict__ out)
{
    const int row = blockIdx.x;           // bi*T + t
    const int bi = row >> 11, t = row & (T_ - 1);
    const int tid = threadIdx.x;
    const size_t elems = (size_t)B_ * T_ * D_;

    const int head = tid >> 4;
    const size_t li = (size_t)(head * B_ + bi) * T_ + t;
    const float l = pl[li] + pl[32 * T_ + li];
    const float inv = 1.0f / fmaxf(l, 1e-30f);

    const size_t basei = (size_t)row * D_ + (tid << 2);
    uint2 a = *(const uint2*)(po + basei);
    uint2 b = *(const uint2*)(po + elems + basei);
    float4 qv = *(const float4*)(qin + basei);
    float x[4];
    x[0] = (bf2f(a.x & 0xffffu) + bf2f(b.x & 0xffffu)) * inv + qv.x;
    x[1] = (bf2f(a.x >> 16)     + bf2f(b.x >> 16))     * inv + qv.y;
    x[2] = (bf2f(a.y & 0xffffu) + bf2f(b.y & 0xffffu)) * inv + qv.z;
    x[3] = (bf2f(a.y >> 16)     + bf2f(b.y >> 16))     * inv + qv.w;

    float s  = x[0] + x[1] + x[2] + x[3];
    float s2 = x[0]*x[0] + x[1]*x[1] + x[2]*x[2] + x[3]*x[3];
    #pragma unroll
    for (int off = 1; off < 64; off <<= 1) {
        s  += __shfl_xor(s, off, 64);
        s2 += __shfl_xor(s2, off, 64);
    }
    __shared__ float rs[4], rs2[4];
    const int wid = tid >> 6;
    if ((tid & 63) == 0) { rs[wid] = s; rs2[wid] = s2; }
    __syncthreads();
    s  = rs[0] + rs[1] + rs[2] + rs[3];
    s2 = rs2[0] + rs2[1] + rs2[2] + rs2[3];
    const float mean = s * (1.0f / (float)D_);
    const float var  = s2 * (1.0f / (float)D_) - mean * mean;
    const float rstd = rsqrtf(var + 1e-5f);
    float4 g = *(const float4*)(gamma + (tid << 2));
    float4 bb = *(const float4*)(beta + (tid << 2));
    float4 r;
    r.x = (x[0] - mean) * rstd * g.x + bb.x;
    r.y = (x[1] - mean) * rstd * g.y + bb.y;
    r.z = (x[2] - mean) * rstd * g.z + bb.z;
    r.w = (x[3] - mean) * rstd * g.w + bb.w;
    *(float4*)(out + basei) = r;
}

extern "C" void kernel_launch(void* const* d_in, const int* in_sizes, int n_in,
                              void* d_out, int out_size, void* d_ws, size_t ws_size,
                              hipStream_t stream)
{
    (void)in_sizes; (void)n_in; (void)out_size; (void)ws_size;
    const float* q    = (const float*)d_in[0];
    const float* k    = (const float*)d_in[1];
    const float* v    = (const float*)d_in[2];
    const int* mask = (const int*)d_in[3];
    const int* caus = (const int*)d_in[4];
    /* d_in[5] = edge_fea (unused) */
    const float* wq = (const float*)d_in[6];
    const float* bq = (const float*)d_in[7];
    const float* wk = (const float*)d_in[8];
    const float* bk = (const float*)d_in[9];
    const float* wv = (const float*)d_in[10];
    const float* bv = (const float*)d_in[11];
    const float* gamma = (const float*)d_in[12];
    const float* beta  = (const float*)d_in[13];
    float* out = (float*)d_out;

    const size_t elems = (size_t)B_ * T_ * D_;   // 4,194,304
    u16* qh  = (u16*)d_ws;
    u16* kh  = qh + elems;
    u16* vt  = kh + elems;                       // transposed V [n][64][T]
    u16* xbf = vt + elems;                       // bf16 X, 3 tensors (dead after proj)
    u16* wbf = xbf + 3 * elems;                  // bf16 W, 3 tensors
    // po/pl reuse the xbf region (proj finished before attn writes them):
    u16* po   = xbf;                             // 2 x elems bf16 partial O
    float* pl = (float*)(po + 2 * elems);        // 2 x 32 x T fp32 partial l

    conv_kernel<<<dim3(512, 6), 256, 0, stream>>>(q, k, v, wq, wk, wv, xbf, wbf);
    proj_mfma<<<dim3(8, 32, 3), 256, 0, stream>>>(xbf, wbf, bq, bk, bv, qh, kh, vt);

    dim3 agrid(T_ / 128, H_ * B_, 2);            // 16 x 32 x 2 = 1024 blocks
    attn_kernel<<<agrid, 256, 0, stream>>>(qh, kh, vt, mask, caus, po, pl);

    fuse_ln<<<B_ * T_, 256, 0, stream>>>(po, pl, q, gamma, beta, out);
}

// Round 9
// 217.530 us; speedup vs baseline: 1.1851x; 1.0761x over previous
//
#include <hip/hip_runtime.h>
#include <hip/hip_bf16.h>
#include <stdint.h>

#define B_ 2
#define T_ 2048
#define D_ 1024
#define H_ 16
#define DEPTH 64

typedef unsigned short u16;
typedef unsigned int u32;
typedef short bf16x8 __attribute__((ext_vector_type(8)));
typedef float f32x4 __attribute__((ext_vector_type(4)));

#define MFMA16(a, b, c) __builtin_amdgcn_mfma_f32_16x16x32_bf16(a, b, c, 0, 0, 0)

// raw v_exp_f32 (1 VALU inst) -- OCML exp2f costs ~10+ insts in fixups we
// don't need (args in [-6.2e9, ~2]; result rounded to bf16 afterwards anyway)
#if __has_builtin(__builtin_amdgcn_exp2f)
#define EXP2(x) __builtin_amdgcn_exp2f(x)
#else
#define EXP2(x) __expf((x) * 0.6931471805599453f)
#endif

// async global->LDS, 16B per lane; LDS dest = wave-uniform base + lane*16
#define GLOAD_LDS(g, l)                                                      \
    __builtin_amdgcn_global_load_lds(                                        \
        (__attribute__((address_space(1))) void*)(g),                        \
        (__attribute__((address_space(3))) void*)(l), 16, 0, 0)

__device__ __forceinline__ float bf2f(u32 u) {
    union { u32 i; float f; } x; x.i = u << 16; return x.f;
}
__device__ __forceinline__ u16 f2bf(float f) {
    union { float f; u32 i; } x; x.f = f;
    u32 r = x.i + 0x7fffu + ((x.i >> 16) & 1u);
    return (u16)(r >> 16);
}
__device__ __forceinline__ uint2 pk4(float4 f) {
    return make_uint2((u32)f2bf(f.x) | ((u32)f2bf(f.y) << 16),
                      (u32)f2bf(f.z) | ((u32)f2bf(f.w) << 16));
}
// round-half-up pack of two floats to packed bf16x2 (2 VALU/value)
__device__ __forceinline__ u32 pkfast(float a, float b) {
    union { float f; u32 i; } x, y; x.f = a; y.f = b;
    return ((y.i + 0x8000u) & 0xffff0000u) | ((x.i + 0x8000u) >> 16);
}

// ---------------------------------------------------------------------------
// fp32 -> bf16 convert: X (q,k,v: 4M each) and W (wq,wk,wv: 1M each)
// ---------------------------------------------------------------------------
__global__ __launch_bounds__(256) void conv_kernel(
    const float* __restrict__ s0, const float* __restrict__ s1, const float* __restrict__ s2,
    const float* __restrict__ s3, const float* __restrict__ s4, const float* __restrict__ s5,
    u16* __restrict__ xbf, u16* __restrict__ wbf)
{
    const int z = blockIdx.y;
    const float* src = (z == 0) ? s0 : (z == 1) ? s1 : (z == 2) ? s2
                     : (z == 3) ? s3 : (z == 4) ? s4 : s5;
    u16* dst = (z < 3) ? (xbf + (size_t)z * 4194304) : (wbf + (size_t)(z - 3) * 1048576);
    const size_t nel = (z < 3) ? 4194304u : 1048576u;
    for (size_t i = ((size_t)blockIdx.x * 256 + threadIdx.x) * 8; i < nel;
         i += (size_t)gridDim.x * 2048) {
        float4 a = *(const float4*)(src + i);
        float4 b = *(const float4*)(src + i + 4);
        uint2 lo = pk4(a), hi = pk4(b);
        *(uint4*)(dst + i) = make_uint4(lo.x, lo.y, hi.x, hi.y);
    }
}

// ---------------------------------------------------------------------------
// Projection: bf16 X @ W^T + bias. 128x128 tile, BK=64, global_load_lds
// width-16, XOR chunk swizzle, single-buffered (3 blocks/CU beats dbuf's 2).
// Q/K head-split [h*B+b][t][64]; V transposed [h*B+b][64][T].
// ---------------------------------------------------------------------------
__global__ __launch_bounds__(256, 3) void proj_mfma(
    const u16* __restrict__ xbf, const u16* __restrict__ wbf,
    const float* __restrict__ bq, const float* __restrict__ bk, const float* __restrict__ bv,
    u16* __restrict__ qh, u16* __restrict__ kh, u16* __restrict__ vt)
{
    __shared__ __attribute__((aligned(16))) u16 As[128 * 64];
    __shared__ __attribute__((aligned(16))) u16 Bs[128 * 64];

    const int z = blockIdx.z;
    const u16* A = xbf + (size_t)z * 4194304;
    const u16* W = wbf + (size_t)z * 1048576;
    const float* bias = (z == 0) ? bq : (z == 1) ? bk : bv;

    const int tid = threadIdx.x, w = tid >> 6, lane = tid & 63;
    const int quad = lane >> 4, l16 = lane & 15;
    const int m0 = blockIdx.y * 128, n0 = blockIdx.x * 128;
    const int wm = (w & 1) * 64, wn = (w >> 1) * 64;
    const int srow = lane >> 3;                 // 0..7
    const int schunk = (lane & 7) ^ srow;       // xor-swizzled source chunk

    f32x4 acc[4][4];
    #pragma unroll
    for (int mi = 0; mi < 4; ++mi)
        #pragma unroll
        for (int ni = 0; ni < 4; ++ni) acc[mi][ni] = (f32x4){0.f, 0.f, 0.f, 0.f};

    const size_t ar = (size_t)(m0 + 32 * w + srow);
    const size_t br = (size_t)(n0 + 32 * w + srow);

    for (int k0 = 0; k0 < D_; k0 += 64) {
        __syncthreads();
        #pragma unroll
        for (int i = 0; i < 4; ++i) {
            GLOAD_LDS(A + (ar + 8 * i) * D_ + k0 + schunk * 8, &As[(32 * w + 8 * i) * 64]);
            GLOAD_LDS(W + (br + 8 * i) * D_ + k0 + schunk * 8, &Bs[(32 * w + 8 * i) * 64]);
        }
        __syncthreads();

        #pragma unroll
        for (int kg = 0; kg < 2; ++kg) {
            const int ch = ((4 * kg + quad) ^ (l16 & 7)) * 8;
            bf16x8 af[4], bf[4];
            #pragma unroll
            for (int mi = 0; mi < 4; ++mi)
                af[mi] = *(const bf16x8*)&As[(wm + 16 * mi + l16) * 64 + ch];
            #pragma unroll
            for (int ni = 0; ni < 4; ++ni)
                bf[ni] = *(const bf16x8*)&Bs[(wn + 16 * ni + l16) * 64 + ch];
            #pragma unroll
            for (int mi = 0; mi < 4; ++mi)
                #pragma unroll
                for (int ni = 0; ni < 4; ++ni)
                    acc[mi][ni] = MFMA16(af[mi], bf[ni], acc[mi][ni]);
        }
    }

    float bl[4];
    #pragma unroll
    for (int ni = 0; ni < 4; ++ni) bl[ni] = bias[n0 + wn + ni * 16 + l16];

    #pragma unroll
    for (int mi = 0; mi < 4; ++mi) {
        const int mb = m0 + wm + mi * 16 + quad * 4;
        #pragma unroll
        for (int ni = 0; ni < 4; ++ni) {
            const int nn = n0 + wn + ni * 16 + l16;
            const int head = nn >> 6, d = nn & 63;
            if (z < 2) {
                u16* outp = (z == 0) ? qh : kh;
                #pragma unroll
                for (int r = 0; r < 4; ++r) {
                    const int m = mb + r;
                    const int b = m >> 11, t = m & (T_ - 1);
                    outp[((size_t)(head * B_ + b) * T_ + t) * DEPTH + d] =
                        f2bf(acc[mi][ni][r] + bl[ni]);
                }
            } else {
                const int b = mb >> 11, t = mb & (T_ - 1);
                float4 f = make_float4(acc[mi][ni][0] + bl[ni], acc[mi][ni][1] + bl[ni],
                                       acc[mi][ni][2] + bl[ni], acc[mi][ni][3] + bl[ni]);
                *(uint2*)(vt + ((size_t)(head * B_ + b) * DEPTH + d) * T_ + t) = pk4(f);
            }
        }
    }
}

// ---------------------------------------------------------------------------
// Flash attention, S^T form, fixed-max softmax, SPLIT-K over 2 key halves
// (partials exactly additive). Tq=128/block, 4 waves x 2 strips. Single-
// buffered K/V via global_load_lds, XOR chunk swizzle. exp via raw v_exp_f32.
// V pre-transposed [n][64][T]. Mask quirk: row n uses mask[n / H].
// ---------------------------------------------------------------------------
__global__ __launch_bounds__(256, 4) void attn_kernel(
    const u16* __restrict__ qh, const u16* __restrict__ kh, const u16* __restrict__ vt,
    const int* __restrict__ maskp, const int* __restrict__ causp,
    u16* __restrict__ po, float* __restrict__ pl)
{
    __shared__ __attribute__((aligned(16))) u16 Ks[64 * 64];       // [key][depth] swizzled
    __shared__ __attribute__((aligned(16))) u16 Vs[64 * 64];       // [depth][key] swizzled
    __shared__ __attribute__((aligned(16))) u16 Ps[4][2][16][72];  // [wave][strip][q][key]
    __shared__ __attribute__((aligned(16))) float padf[1024];      // mask*PAD, this half

    const int n  = blockIdx.y;          // head*B + b
    const int qt = blockIdx.x;          // 128-query tile
    const int kk = blockIdx.z;          // key half
    const int kbase = kk * 1024;
    const int head = n >> 1, bi = n & 1;
    const int mrow = n >> 4;            // n / H  (reference repeat quirk)
    const int caus = causp[0];

    const int tid  = threadIdx.x;
    const int w    = tid >> 6, lane = tid & 63;
    const int quad = lane >> 4, l16 = lane & 15;
    const size_t base = (size_t)n * T_ * DEPTH;
    const size_t vbase = (size_t)n * DEPTH * T_;
    const size_t elems = (size_t)B_ * T_ * D_;

    const float C1  = 0.18033688011112042f;   // (1/8) * log2(e)
    const float PL2 = -6.2e9f;                // exp2 -> 0

    // precompute pad row for this key half (once per block)
    {
        const int i0 = tid * 4;
        int4 m = *(const int4*)(maskp + (size_t)mrow * T_ + kbase + i0);
        padf[i0 + 0] = (float)m.x * PL2; padf[i0 + 1] = (float)m.y * PL2;
        padf[i0 + 2] = (float)m.z * PL2; padf[i0 + 3] = (float)m.w * PL2;
    }

    // Q fragments: 2 strips x 2 k-halves, loop-invariant registers
    bf16x8 aq[2][2];
    #pragma unroll
    for (int s = 0; s < 2; ++s) {
        const int qg = qt * 128 + w * 32 + s * 16 + l16;
        aq[s][0] = *(const bf16x8*)(qh + base + (size_t)qg * DEPTH + quad * 8);
        aq[s][1] = *(const bf16x8*)(qh + base + (size_t)qg * DEPTH + 32 + quad * 8);
    }

    f32x4 O[2][4];
    #pragma unroll
    for (int s = 0; s < 2; ++s)
        #pragma unroll
        for (int t = 0; t < 4; ++t) O[s][t] = (f32x4){0.f, 0.f, 0.f, 0.f};
    float lp[2] = {0.f, 0.f};

    // staging addresses: wave w stages tile rows w*16..w*16+15
    const int g_row = w * 16 + (lane >> 3);           // tile row this lane feeds
    const int g_ch  = (lane & 7) ^ ((lane >> 3) & 7); // swizzled source chunk
    const u16* ksrc = kh + base + (size_t)g_row * DEPTH + g_ch * 8;
    const u16* vsrc = vt + vbase + (size_t)g_row * T_ + g_ch * 8;

    for (int t0 = kbase; t0 < kbase + 1024; t0 += 64) {
        __syncthreads();   // prev compute done (also covers padf on 1st iter)
        GLOAD_LDS(ksrc + (size_t)t0 * DEPTH,       &Ks[(w * 16) * 64]);
        GLOAD_LDS(ksrc + (size_t)(t0 + 8) * DEPTH, &Ks[(w * 16 + 8) * 64]);
        GLOAD_LDS(vsrc + t0,                       &Vs[(w * 16) * 64]);
        GLOAD_LDS(vsrc + (size_t)8 * T_ + t0,      &Vs[(w * 16 + 8) * 64]);
        __syncthreads();

        // S^T per 16-key subtile; exp; P -> LDS
        const int swz = (l16 & 7);
        const int lt0 = t0 - kbase;
        #pragma unroll
        for (int t = 0; t < 4; ++t) {
            const int krow = t * 16 + l16;
            bf16x8 kb0 = *(const bf16x8*)&Ks[krow * 64 + ((quad ^ swz) * 8)];
            bf16x8 kb1 = *(const bf16x8*)&Ks[krow * 64 + (((4 + quad) ^ swz) * 8)];
            f32x4 pv4 = *(const f32x4*)&padf[lt0 + t * 16 + quad * 4];
            #pragma unroll
            for (int s = 0; s < 2; ++s) {
                f32x4 st = (f32x4){0.f, 0.f, 0.f, 0.f};
                st = MFMA16(kb0, aq[s][0], st);
                st = MFMA16(kb1, aq[s][1], st);
                float v0 = fmaf(st[0], C1, pv4[0]);
                float v1 = fmaf(st[1], C1, pv4[1]);
                float v2 = fmaf(st[2], C1, pv4[2]);
                float v3 = fmaf(st[3], C1, pv4[3]);
                if (caus) {
                    const int kg = t0 + t * 16 + quad * 4;
                    const int qg = qt * 128 + w * 32 + s * 16 + l16;
                    if (kg + 0 > qg) v0 = PL2;
                    if (kg + 1 > qg) v1 = PL2;
                    if (kg + 2 > qg) v2 = PL2;
                    if (kg + 3 > qg) v3 = PL2;
                }
                const float e0 = EXP2(v0), e1 = EXP2(v1);
                const float e2 = EXP2(v2), e3 = EXP2(v3);
                lp[s] += (e0 + e1) + (e2 + e3);
                *(uint2*)&Ps[w][s][l16][t * 16 + quad * 4] =
                    make_uint2(pkfast(e0, e1), pkfast(e2, e3));
            }
        }

        // PV: O[s][query][d] += P * V  (same-wave Ps reuse, no barrier)
        bf16x8 ap[2][2];
        #pragma unroll
        for (int s = 0; s < 2; ++s) {
            ap[s][0] = *(const bf16x8*)&Ps[w][s][l16][quad * 8];
            ap[s][1] = *(const bf16x8*)&Ps[w][s][l16][32 + quad * 8];
        }
        #pragma unroll
        for (int t = 0; t < 4; ++t) {
            const int drow = t * 16 + l16;
            bf16x8 vb0 = *(const bf16x8*)&Vs[drow * 64 + ((quad ^ swz) * 8)];
            bf16x8 vb1 = *(const bf16x8*)&Vs[drow * 64 + (((4 + quad) ^ swz) * 8)];
            #pragma unroll
            for (int s = 0; s < 2; ++s) {
                O[s][t] = MFMA16(ap[s][0], vb0, O[s][t]);
                O[s][t] = MFMA16(ap[s][1], vb1, O[s][t]);
            }
        }
    }

    // fold l across quads; write partial l
    u16* pop = po + (size_t)kk * elems;
    float* plp = pl + (size_t)kk * 32 * T_;
    #pragma unroll
    for (int s = 0; s < 2; ++s) {
        lp[s] += __shfl_xor(lp[s], 16, 64);
        lp[s] += __shfl_xor(lp[s], 32, 64);
        if (quad == 0)
            plp[(size_t)n * T_ + qt * 128 + w * 32 + s * 16 + l16] = lp[s];
    }

    // write partial O (bf16, un-normalized)
    #pragma unroll
    for (int s = 0; s < 2; ++s) {
        #pragma unroll
        for (int r = 0; r < 4; ++r) {
            const int qg = qt * 128 + w * 32 + s * 16 + quad * 4 + r;
            const size_t rb = ((size_t)bi * T_ + qg) * D_ + head * DEPTH + l16;
            pop[rb + 0]  = f2bf(O[s][0][r]);
            pop[rb + 16] = f2bf(O[s][1][r]);
            pop[rb + 32] = f2bf(O[s][2][r]);
            pop[rb + 48] = f2bf(O[s][3][r]);
        }
    }
}

// ---------------------------------------------------------------------------
// Fused combine + residual + LayerNorm: x = (po0+po1)/(l0+l1) + q; LN over D.
// ---------------------------------------------------------------------------
__global__ __launch_bounds__(256) void fuse_ln(
    const u16* __restrict__ po, const float* __restrict__ pl,
    const float* __restrict__ qin,
    const float* __restrict__ gamma, const float* __restrict__ beta,
    float* __restrict__ out)
{
    const int row = blockIdx.x;           // bi*T + t
    const int bi = row >> 11, t = row & (T_ - 1);
    const int tid = threadIdx.x;
    const size_t elems = (size_t)B_ * T_ * D_;

    const int head = tid >> 4;
    const size_t li = (size_t)(head * B_ + bi) * T_ + t;
    const float l = pl[li] + pl[32 * T_ + li];
    const float inv = 1.0f / fmaxf(l, 1e-30f);

    const size_t basei = (size_t)row * D_ + (tid << 2);
    uint2 a = *(const uint2*)(po + basei);
    uint2 b = *(const uint2*)(po + elems + basei);
    float4 qv = *(const float4*)(qin + basei);
    float x[4];
    x[0] = (bf2f(a.x & 0xffffu) + bf2f(b.x & 0xffffu)) * inv + qv.x;
    x[1] = (bf2f(a.x >> 16)     + bf2f(b.x >> 16))     * inv + qv.y;
    x[2] = (bf2f(a.y & 0xffffu) + bf2f(b.y & 0xffffu)) * inv + qv.z;
    x[3] = (bf2f(a.y >> 16)     + bf2f(b.y >> 16))     * inv + qv.w;

    float s  = x[0] + x[1] + x[2] + x[3];
    float s2 = x[0]*x[0] + x[1]*x[1] + x[2]*x[2] + x[3]*x[3];
    #pragma unroll
    for (int off = 1; off < 64; off <<= 1) {
        s  += __shfl_xor(s, off, 64);
        s2 += __shfl_xor(s2, off, 64);
    }
    __shared__ float rs[4], rs2[4];
    const int wid = tid >> 6;
    if ((tid & 63) == 0) { rs[wid] = s; rs2[wid] = s2; }
    __syncthreads();
    s  = rs[0] + rs[1] + rs[2] + rs[3];
    s2 = rs2[0] + rs2[1] + rs2[2] + rs2[3];
    const float mean = s * (1.0f / (float)D_);
    const float var  = s2 * (1.0f / (float)D_) - mean * mean;
    const float rstd = rsqrtf(var + 1e-5f);
    float4 g = *(const float4*)(gamma + (tid << 2));
    float4 bb = *(const float4*)(beta + (tid << 2));
    float4 r;
    r.x = (x[0] - mean) * rstd * g.x + bb.x;
    r.y = (x[1] - mean) * rstd * g.y + bb.y;
    r.z = (x[2] - mean) * rstd * g.z + bb.z;
    r.w = (x[3] - mean) * rstd * g.w + bb.w;
    *(float4*)(out + basei) = r;
}

extern "C" void kernel_launch(void* const* d_in, const int* in_sizes, int n_in,
                              void* d_out, int out_size, void* d_ws, size_t ws_size,
                              hipStream_t stream)
{
    (void)in_sizes; (void)n_in; (void)out_size; (void)ws_size;
    const float* q    = (const float*)d_in[0];
    const float* k    = (const float*)d_in[1];
    const float* v    = (const float*)d_in[2];
    const int* mask = (const int*)d_in[3];
    const int* caus = (const int*)d_in[4];
    /* d_in[5] = edge_fea (unused) */
    const float* wq = (const float*)d_in[6];
    const float* bq = (const float*)d_in[7];
    const float* wk = (const float*)d_in[8];
    const float* bk = (const float*)d_in[9];
    const float* wv = (const float*)d_in[10];
    const float* bv = (const float*)d_in[11];
    const float* gamma = (const float*)d_in[12];
    const float* beta  = (const float*)d_in[13];
    float* out = (float*)d_out;

    const size_t elems = (size_t)B_ * T_ * D_;   // 4,194,304
    u16* qh  = (u16*)d_ws;
    u16* kh  = qh + elems;
    u16* vt  = kh + elems;                       // transposed V [n][64][T]
    u16* xbf = vt + elems;                       // bf16 X, 3 tensors (dead after proj)
    u16* wbf = xbf + 3 * elems;                  // bf16 W, 3 tensors
    // po/pl reuse the xbf region (proj finished before attn writes them):
    u16* po   = xbf;                             // 2 x elems bf16 partial O
    float* pl = (float*)(po + 2 * elems);        // 2 x 32 x T fp32 partial l

    conv_kernel<<<dim3(512, 6), 256, 0, stream>>>(q, k, v, wq, wk, wv, xbf, wbf);
    proj_mfma<<<dim3(8, 32, 3), 256, 0, stream>>>(xbf, wbf, bq, bk, bv, qh, kh, vt);

    dim3 agrid(T_ / 128, H_ * B_, 2);            // 16 x 32 x 2 = 1024 blocks
    attn_kernel<<<agrid, 256, 0, stream>>>(qh, kh, vt, mask, caus, po, pl);

    fuse_ln<<<B_ * T_, 256, 0, stream>>>(po, pl, q, gamma, beta, out);
}